// Round 6
// baseline (2357.323 us; speedup 1.0000x reference)
//
#include <hip/hip_runtime.h>
#include <stdint.h>

typedef unsigned short u16;
typedef __bf16 bf16x8 __attribute__((ext_vector_type(8)));
typedef float f32x4 __attribute__((ext_vector_type(4)));

#define AS1 __attribute__((address_space(1)))
#define AS3 __attribute__((address_space(3)))

__device__ __forceinline__ void ld_lds16(const void* gp, void* lp) {
  __builtin_amdgcn_global_load_lds((AS1 void*)(void*)gp, (AS3 void*)lp, 16, 0, 0);
}

__device__ __forceinline__ u16 f2bf(float f) {
  uint32_t u = __float_as_uint(f);
  u += 0x7FFFu + ((u >> 16) & 1u);
  return (u16)(u >> 16);
}

__device__ __forceinline__ float fsig(float x) { return 1.0f / (1.0f + __expf(-x)); }
__device__ __forceinline__ float ftanhf(float x) {
  float e = __expf(-2.0f * fabsf(x));
  float t = (1.0f - e) / (1.0f + e);
  return copysignf(t, x);
}

#define LSEQ 100
#define EMB 512
#define HID 1024
#define KDIM 1536

// ---------------- LSTM step ----------------
// z = [x_t; h] @ W' with W in FRAGMENT-MAJOR layout loaded direct to VGPRs (no LDS for B).
// A (gathered [x_t;h]) staged via global_load_lds into 4-buf LDS pipeline (64 KB total).
// 8 waves = 2m x 4n (wave tile 64x32). Gate perm: n' = (h>>3)*32 + g*8 + (h&7);
// lane owns gates {i,f} (lane&8==0) or {j,o}; partner lane^8 supplies the other two via shfl_xor.
// Full 24-iter unroll; counted vmcnt groups of 6 (2 A-stage + 4 B-loads); waits 12/12/6/0.
__global__ __launch_bounds__(512, 2) void k_step(
    const u16* __restrict__ emb, const u16* __restrict__ Wfm,
    const float* __restrict__ b2, const float* __restrict__ p_i,
    const float* __restrict__ p_f, const float* __restrict__ p_o,
    const int* __restrict__ tokQ, const int* __restrict__ tokR,
    const int* __restrict__ lenQ, const int* __restrict__ lenR,
    const u16* __restrict__ h_cur, u16* __restrict__ h_nxt,
    float* __restrict__ c_st, int t)
{
  __shared__ u16 sb[4 * 8192];  // 4 A-bufs x 16 KB = 64 KB
  const int tid = threadIdx.x;
  const int lane = tid & 63, wid = tid >> 6;       // 8 waves
  const int wm = wid >> 2, wn = wid & 3;           // 2m x 4n; wave tile 64 rows x 32 cols
  const int lane_lo = lane & 15, lane_hi = lane >> 4;
  // XCD-aware swizzle: XCD k (= g%8) owns bx in {4k..4k+3}, all by.
  const int g = blockIdx.x;
  const int bx = (g & 7) * 4 + ((g >> 3) & 3);
  const int by = g >> 5;

  f32x4 acc[4][2];
  const f32x4 zz = {0.f, 0.f, 0.f, 0.f};
#pragma unroll
  for (int a = 0; a < 4; ++a)
#pragma unroll
    for (int bb = 0; bb < 2; ++bb) acc[a][bb] = zz;

  // ---- token loads FIRST (longest dependency chain) ----
  int tokv[2], rowe[2], rowi[2], ldso[2], srco[2];
#pragma unroll
  for (int j = 0; j < 2; ++j) {
    const int ch = j * 512 + tid;        // chunk 0..1023; 8 chunks (128 B) per row
    const int r = ch >> 3;
    const int srcoff = ((ch & 7) ^ (r & 7)) * 8;   // zero-conflict XOR swizzle (u16 elems)
    const int m = by * 128 + r, e = m >> 9, i = m & 511;
    tokv[j] = (e ? tokR : tokQ)[i * LSEQ + t];
    rowe[j] = e; rowi[j] = i;
    srco[j] = srcoff;
    ldso[j] = ch * 8;                    // linear LDS dest (u16)
  }

  // ---- per-lane h-unit & epilogue operand prefetch (oldest in vmcnt; hidden under K-loop) ----
  const int h = (bx * 4 + wn) * 8 + (lane & 7);
  float b2v[2];
#pragma unroll
  for (int ni = 0; ni < 2; ++ni) b2v[ni] = b2[bx * 128 + wn * 32 + ni * 16 + lane_lo];
  const float pi = p_i[h], pf = p_f[h], po = p_o[h];
  int lenv[4][4];
  float cold[4][4];
  u16 hprev[4][4];
#pragma unroll
  for (int mi = 0; mi < 4; ++mi)
#pragma unroll
    for (int r = 0; r < 4; ++r) {
      const int m = by * 128 + wm * 64 + mi * 16 + lane_hi * 4 + r;
      const int e = m >> 9, i = m & 511;
      lenv[mi][r] = e ? lenR[i] : lenQ[i];
      const size_t ci = (size_t)(e * 512 + i) * HID + h;
      cold[mi][r] = c_st[ci];
      hprev[mi][r] = h_cur[ci];
    }
  __builtin_amdgcn_sched_barrier(0);  // pin: prologue vmem issued before staging

  // ---- staging pointers ----
  const u16* pAx[2];
  const u16* pAh[2];
#pragma unroll
  for (int j = 0; j < 2; ++j) {
    pAx[j] = emb + (size_t)tokv[j] * EMB + srco[j];
    pAh[j] = h_cur + (size_t)(rowe[j] * 512 + rowi[j]) * HID - 512 + srco[j];  // kb>=512 when used
  }
  const u16* pWl = Wfm + (size_t)(bx * 4 + wn) * 49152 + lane * 8;  // fragment-major wave base

  bf16x8 Bst[3][4];  // 3 in-flight K-groups x (kk,ni) — statically indexed (full unroll)

  auto stageA = [&](int kt) {
    const int kb = kt * 64;
    u16* lA = sb + (kt & 3) * 8192;
    const bool isx = kb < EMB;  // compile-time after unroll
#pragma unroll
    for (int j = 0; j < 2; ++j) ld_lds16((isx ? pAx[j] : pAh[j]) + kb, lA + ldso[j]);
  };

  auto loadB = [&](int kt) {
    const int s = kt % 3;
#pragma unroll
    for (int q = 0; q < 4; ++q)
      Bst[s][q] = *(const bf16x8*)(pWl + kt * 2048 + q * 512);
  };

  auto compute = [&](int kt) {
    const char* lA = (const char*)(sb + (kt & 3) * 8192);
    const int s = kt % 3;
#pragma unroll
    for (int kk = 0; kk < 2; ++kk) {
      bf16x8 aF[4];
#pragma unroll
      for (int mi = 0; mi < 4; ++mi) {
        const int rr = wm * 64 + mi * 16 + lane_lo;
        const int byo = rr * 128 + ((kk * 64 + lane_hi * 16) ^ ((rr & 7) << 4));
        aF[mi] = *(const bf16x8*)(lA + byo);
      }
#pragma unroll
      for (int mi = 0; mi < 4; ++mi)
#pragma unroll
        for (int ni = 0; ni < 2; ++ni)
          acc[mi][ni] = __builtin_amdgcn_mfma_f32_16x16x32_bf16(aF[mi], Bst[s][kk * 2 + ni], acc[mi][ni], 0, 0, 0);
    }
  };

  // ---- prologue: 3 groups in flight (A0 B0 A1 B1 A2 B2 = 18 vmem) ----
  stageA(0); loadB(0);
  stageA(1); loadB(1);
  stageA(2); loadB(2);

  // ---- K loop, fully unrolled: wait group kt, barrier, stage A(kt+3), MFMA, load B(kt+3) ----
#pragma unroll
  for (int kt = 0; kt < 24; ++kt) {
    if (kt <= 21)      asm volatile("s_waitcnt vmcnt(12)" ::: "memory");
    else if (kt == 22) asm volatile("s_waitcnt vmcnt(6)" ::: "memory");
    else               asm volatile("s_waitcnt vmcnt(0)" ::: "memory");
    __builtin_amdgcn_s_barrier();
    __builtin_amdgcn_sched_barrier(0);
    if (kt < 21) stageA(kt + 3);
    __builtin_amdgcn_s_setprio(1);
    compute(kt);
    __builtin_amdgcn_s_setprio(0);
    __builtin_amdgcn_sched_barrier(0);
    if (kt < 21) loadB(kt + 3);  // after compute(kt): Bst[kt%3] reuse is WAR-safe
  }

  // ----- fused gate epilogue: shfl_xor(8) pairs reconstitute all 4 gates per h-unit -----
#pragma unroll
  for (int mi = 0; mi < 4; ++mi)
#pragma unroll
    for (int ni = 0; ni < 2; ++ni)
#pragma unroll
      for (int r = 0; r < 4; ++r) acc[mi][ni][r] += b2v[ni];  // bias (incl. forget bias) pre-shuffle

  const bool lo8 = (lane & 8) == 0;   // owns {i,f}; partner owns {j,o}
#pragma unroll
  for (int mi = 0; mi < 4; ++mi) {
#pragma unroll
    for (int r = 0; r < 4; ++r) {
      const float a0 = acc[mi][0][r], a1 = acc[mi][1][r];
      const float p0 = __shfl_xor(a0, 8);
      const float p1 = __shfl_xor(a1, 8);
      const float zi = lo8 ? a0 : p0;
      const float zf = lo8 ? a1 : p1;
      const float zj = lo8 ? p0 : a0;
      const float zo = lo8 ? p1 : a1;
      const int m = by * 128 + wm * 64 + mi * 16 + lane_hi * 4 + r;
      const int e = m >> 9, i = m & 511;
      const size_t ci = (size_t)(e * 512 + i) * HID + h;
      if (t < lenv[mi][r]) {
        const float c_old = cold[mi][r];
        const float ig = fsig(zi + pi * c_old);
        const float fg = fsig(zf + pf * c_old);
        const float cn = fg * c_old + ig * ftanhf(zj);
        const float og = fsig(zo + po * cn);
        const float hn = og * ftanhf(cn);
        if (lo8) { c_st[ci] = cn; h_nxt[ci] = f2bf(hn); }
      } else {
        if (lo8) h_nxt[ci] = hprev[mi][r];
      }
    }
  }
}

// ---------------- generic bf16 GEMM: C[m][n] = sum_k A[m][k] * Bn[n][k] ----------------
template <int OUT_BF16>
__global__ __launch_bounds__(256) void k_gemm(
    const u16* __restrict__ A, const u16* __restrict__ Bn,
    void* __restrict__ Cout, int K, int ldc)
{
  __shared__ u16 lA[128 * 64];
  __shared__ u16 lB[128 * 64];
  const int tid = threadIdx.x;
  const int lane = tid & 63, wid = tid >> 6;
  const int wm = wid >> 1, wn = wid & 1;
  const int lane_lo = lane & 15, lane_hi = lane >> 4;
  const int bx = blockIdx.x, by = blockIdx.y;

  f32x4 acc[4][4];
  const f32x4 zz = {0.f, 0.f, 0.f, 0.f};
#pragma unroll
  for (int a = 0; a < 4; ++a)
#pragma unroll
    for (int bb = 0; bb < 4; ++bb) acc[a][bb] = zz;

  const int nkt = K >> 6;
  for (int kt = 0; kt < nkt; ++kt) {
    const int kb = kt * 64;
#pragma unroll
    for (int j = 0; j < 4; ++j) {
      const int cbase = (j * 4 + wid) * 64;
      const int ch = cbase + lane;
      const int r = ch >> 3;
      const int srcoff = ((((ch & 7) << 4) ^ ((r & 7) << 4)) >> 1);
      ld_lds16(A + (size_t)(by * 128 + r) * K + kb + srcoff, &lA[cbase * 8]);
    }
#pragma unroll
    for (int j = 0; j < 4; ++j) {
      const int cbase = (j * 4 + wid) * 64;
      const int ch = cbase + lane;
      const int r = ch >> 3;
      const int srcoff = ((((ch & 7) << 4) ^ ((r & 7) << 4)) >> 1);
      ld_lds16(Bn + (size_t)(bx * 128 + r) * K + kb + srcoff, &lB[cbase * 8]);
    }
    __syncthreads();
#pragma unroll
    for (int kk = 0; kk < 2; ++kk) {
      bf16x8 aF[4], bF[4];
#pragma unroll
      for (int mi = 0; mi < 4; ++mi) {
        const int rr = wm * 64 + mi * 16 + lane_lo;
        const int byo = rr * 128 + ((kk * 64 + lane_hi * 16) ^ ((rr & 7) << 4));
        aF[mi] = *(const bf16x8*)((const char*)lA + byo);
      }
#pragma unroll
      for (int ni = 0; ni < 4; ++ni) {
        const int rr = wn * 64 + ni * 16 + lane_lo;
        const int byo = rr * 128 + ((kk * 64 + lane_hi * 16) ^ ((rr & 7) << 4));
        bF[ni] = *(const bf16x8*)((const char*)lB + byo);
      }
#pragma unroll
      for (int mi = 0; mi < 4; ++mi)
#pragma unroll
        for (int ni = 0; ni < 4; ++ni)
          acc[mi][ni] = __builtin_amdgcn_mfma_f32_16x16x32_bf16(aF[mi], bF[ni], acc[mi][ni], 0, 0, 0);
    }
    __syncthreads();
  }

#pragma unroll
  for (int mi = 0; mi < 4; ++mi)
#pragma unroll
    for (int r = 0; r < 4; ++r) {
      const int m = by * 128 + wm * 64 + mi * 16 + lane_hi * 4 + r;
#pragma unroll
      for (int ni = 0; ni < 4; ++ni) {
        const int col = bx * 128 + wn * 64 + ni * 16 + lane_lo;
        const float v = acc[mi][ni][r];
        if (OUT_BF16) ((u16*)Cout)[(size_t)m * ldc + col] = f2bf(v);
        else ((float*)Cout)[(size_t)m * ldc + col] = v;
      }
    }
}

// ---------------- prep kernels ----------------
// Fragment-major W pack: Wfm[(((wq*24+kt)*4 + kk*2+ni)*64 + lane)*8 + e] = bf16(W[k][n])
// where n' = wq*32 + ni*16 + lane_lo encodes gate perm n' = (h>>3)*32 + g*8 + (h&7),
// k = kt*64 + kk*32 + lane_hi*8 + e.
__global__ void k_pack(const float* __restrict__ W, u16* __restrict__ Wfm) {
  __shared__ float tile[64][65];
  const int n0 = blockIdx.x * 64;   // 64 tiles over n (orig cols)
  const int k0 = blockIdx.y * 64;   // 24 tiles over k
  const int tid = threadIdx.x;
  const int c = tid & 63, rq = tid >> 6;
  for (int rr = 0; rr < 64; rr += 4)
    tile[rr + rq][c] = W[(size_t)(k0 + rr + rq) * 4096 + n0 + c];
  __syncthreads();
  const int g = n0 >> 10;         // gate (n0 64-aligned within a 1024 gate block)
  const int h0 = n0 & 1023;       // base h (64-aligned)
  const int kt = k0 >> 6;
  for (int cc = tid; cc < 512; cc += 256) {   // 512 chunks of 16 B
    const int hg = cc >> 6;          // (h - h0) >> 3
    const int h7 = (cc >> 3) & 7;    // h & 7
    const int k8 = cc & 7;           // k chunk-of-8 within tile
    const int wq = (h0 >> 3) + hg;
    const int gl = g * 8 + h7;
    const int lane = (k8 & 3) * 16 + (gl & 15);
    const int ni = gl >> 4;
    const int kk = k8 >> 2;
    u16 oc[8];
#pragma unroll
    for (int e = 0; e < 8; ++e)
      oc[e] = f2bf(tile[k8 * 8 + e][hg * 8 + h7]);
    const size_t o = ((((size_t)wq * 24 + kt) * 4 + kk * 2 + ni) * 64 + lane) * 8;
    *(ushort4*)(Wfm + o)     = *(ushort4*)&oc[0];
    *(ushort4*)(Wfm + o + 4) = *(ushort4*)&oc[4];
  }
}

// out[n'][k] (bf16) = in[k][n] (f32), no permutation (used for M^T)
__global__ void k_transpose(const float* __restrict__ in, u16* __restrict__ out,
                            int K_, int N_)
{
  __shared__ float tile[64][65];
  const int tid = threadIdx.x;
  const int k0 = blockIdx.y * 64, n0 = blockIdx.x * 64;
  const int c = tid & 63, rq = tid >> 6;
  for (int rr = 0; rr < 64; rr += 4)
    tile[rr + rq][c] = in[(size_t)(k0 + rr + rq) * N_ + n0 + c];
  __syncthreads();
  for (int nr0 = 0; nr0 < 64; nr0 += 4) {
    const int nr = nr0 + rq;
    out[(size_t)(n0 + nr) * K_ + k0 + c] = f2bf(tile[c][nr]);
  }
}

// b2[n'] = b[g*1024+h] + FORGET_BIAS*(g==2), gate perm n' = (h>>3)*32 + g*8 + (h&7)
__global__ void k_bias(const float* __restrict__ b, float* __restrict__ b2) {
  const int np = blockIdx.x * 256 + threadIdx.x;
  if (np < 4096) {
    const int g = (np >> 3) & 3;
    const int h = (np >> 5) * 8 + (np & 7);
    b2[np] = b[g * 1024 + h] + (g == 2 ? 2.0f : 0.0f);
  }
}

__global__ void k_cvt(const float4* __restrict__ in, u16* __restrict__ out, size_t n4) {
  size_t idx = (size_t)blockIdx.x * blockDim.x + threadIdx.x;
  const size_t stride = (size_t)gridDim.x * blockDim.x;
  for (; idx < n4; idx += stride) {
    const float4 v = in[idx];
    ushort4 o;
    o.x = f2bf(v.x); o.y = f2bf(v.y); o.z = f2bf(v.z); o.w = f2bf(v.w);
    *(ushort4*)(out + idx * 4) = o;
  }
}

__global__ void k_zero(uint4* __restrict__ p, size_t n) {
  size_t idx = (size_t)blockIdx.x * blockDim.x + threadIdx.x;
  const size_t stride = (size_t)gridDim.x * blockDim.x;
  const uint4 z = {0u, 0u, 0u, 0u};
  for (; idx < n; idx += stride) p[idx] = z;
}

// ---------------- loss ----------------
__global__ void k_loss1(const float* __restrict__ D, float* __restrict__ part) {
  __shared__ float sd[256];
  const int tid = threadIdx.x;
  float s = 0.f;
  for (int idx = blockIdx.x * 256 + tid; idx < 512 * 512; idx += 256 * 256) {
    const float x = D[idx];
    float sp;
    if (x > 20.f) sp = x;
    else if (x < -20.f) sp = __expf(x);
    else sp = __logf(1.0f + __expf(x));
    if ((idx >> 9) == (idx & 511)) sp -= x;
    s += sp;
  }
  sd[tid] = s;
  __syncthreads();
  for (int o = 128; o > 0; o >>= 1) { if (tid < o) sd[tid] += sd[tid + o]; __syncthreads(); }
  if (tid == 0) part[blockIdx.x] = sd[0];
}

__global__ void k_loss2(const float* __restrict__ part, float* __restrict__ out) {
  __shared__ float sd[256];
  const int tid = threadIdx.x;
  sd[tid] = part[tid];
  __syncthreads();
  for (int o = 128; o > 0; o >>= 1) { if (tid < o) sd[tid] += sd[tid + o]; __syncthreads(); }
  if (tid == 0) out[0] = sd[0] * (1.0f / (512.0f * 512.0f));
}

// ---------------- launch ----------------
extern "C" void kernel_launch(void* const* d_in, const int* in_sizes, int n_in,
                              void* d_out, int out_size, void* d_ws, size_t ws_size,
                              hipStream_t stream)
{
  const float* embF = (const float*)d_in[0];
  const float* W    = (const float*)d_in[1];
  const float* b    = (const float*)d_in[2];
  const float* p_i  = (const float*)d_in[3];
  const float* p_f  = (const float*)d_in[4];
  const float* p_o  = (const float*)d_in[5];
  const float* Mm   = (const float*)d_in[6];
  const int* tokQ   = (const int*)d_in[7];
  const int* tokR   = (const int*)d_in[8];
  const int* lenQ   = (const int*)d_in[9];
  const int* lenR   = (const int*)d_in[10];
  float* out = (float*)d_out;

  char* ws = (char*)d_ws;
  const size_t OFF_EMB  = 0;                       // 50000*512*2 = 51,200,000
  const size_t OFF_WFM  = 51200000;                // 4096*1536*2 = 12,582,912 (fragment-major)
  const size_t OFF_MT   = OFF_WFM + 12582912;      // 1024*1024*2 =  2,097,152
  const size_t OFF_B2   = OFF_MT + 2097152;        // 4096*4
  const size_t OFF_H    = OFF_B2 + 16384;          // 2buf*2enc*512*1024*2 = 4,194,304
  const size_t OFF_C    = OFF_H + 4194304;         // 2enc*512*1024*4 = 4,194,304
  const size_t OFF_QT   = OFF_C + 4194304;         // 512*1024*2 = 1,048,576
  const size_t OFF_PART = OFF_QT + 1048576;        // 256*4
  const size_t NEED = OFF_PART + 1024;
  if (ws_size < NEED) return;  // workspace too small: bail (output stays invalid as a signal)

  u16* embB  = (u16*)(ws + OFF_EMB);
  u16* Wfm   = (u16*)(ws + OFF_WFM);
  u16* MT    = (u16*)(ws + OFF_MT);
  float* b2  = (float*)(ws + OFF_B2);
  u16* hbuf  = (u16*)(ws + OFF_H);
  float* cst = (float*)(ws + OFF_C);
  u16* qt    = (u16*)(ws + OFF_QT);
  float* part= (float*)(ws + OFF_PART);

  // prep
  k_cvt<<<dim3(2048), dim3(256), 0, stream>>>((const float4*)embF, embB, (size_t)(50000 * 512 / 4));
  k_pack<<<dim3(64, 24), dim3(256), 0, stream>>>(W, Wfm);
  k_transpose<<<dim3(16, 16), dim3(256), 0, stream>>>(Mm, MT, 1024, 1024);
  k_bias<<<dim3(16), dim3(256), 0, stream>>>(b, b2);
  k_zero<<<dim3(256), dim3(256), 0, stream>>>((uint4*)hbuf, 131072);   // h buf0 (2 MB)
  k_zero<<<dim3(256), dim3(256), 0, stream>>>((uint4*)cst, 262144);    // c (4 MB)

  // recurrence: h double-buffered; t reads buf (t&1), writes buf ((t+1)&1); final state in buf 0
  const size_t HBUFSTRIDE = (size_t)2 * 512 * 1024;  // u16 elems per buffer
  for (int t = 0; t < 100; ++t) {
    u16* hc = hbuf + (size_t)(t & 1) * HBUFSTRIDE;
    u16* hn = hbuf + (size_t)((t + 1) & 1) * HBUFSTRIDE;
    k_step<<<dim3(256), dim3(512), 0, stream>>>(embB, Wfm, b2, p_i, p_f, p_o,
                                                tokQ, tokR, lenQ, lenR, hc, hn, cst, t);
  }

  // q_t = h_q @ M  (A = enc0 of buf0; B = M^T rows)
  k_gemm<1><<<dim3(8, 4), dim3(256), 0, stream>>>(hbuf, MT, qt, 1024, 1024);
  // distances = q_t @ h_r^T  (B rows = enc1 final h)
  k_gemm<0><<<dim3(4, 4), dim3(256), 0, stream>>>(qt, hbuf + (size_t)512 * 1024, out, 1024, 512);

  k_loss1<<<dim3(256), dim3(256), 0, stream>>>(out, part);
  k_loss2<<<dim3(1), dim3(256), 0, stream>>>(part, out + 262144);
}

// Round 7
// 2105.000 us; speedup vs baseline: 1.1199x; 1.1199x over previous
//
#include <hip/hip_runtime.h>
#include <stdint.h>

typedef unsigned short u16;
typedef __bf16 bf16x8 __attribute__((ext_vector_type(8)));
typedef float f32x4 __attribute__((ext_vector_type(4)));

#define AS1 __attribute__((address_space(1)))
#define AS3 __attribute__((address_space(3)))

__device__ __forceinline__ void ld_lds16(const void* gp, void* lp) {
  __builtin_amdgcn_global_load_lds((AS1 void*)(void*)gp, (AS3 void*)lp, 16, 0, 0);
}

__device__ __forceinline__ u16 f2bf(float f) {
  uint32_t u = __float_as_uint(f);
  u += 0x7FFFu + ((u >> 16) & 1u);
  return (u16)(u >> 16);
}

__device__ __forceinline__ float fsig(float x) { return 1.0f / (1.0f + __expf(-x)); }
__device__ __forceinline__ float ftanhf(float x) {
  float e = __expf(-2.0f * fabsf(x));
  float t = (1.0f - e) / (1.0f + e);
  return copysignf(t, x);
}

#define LSEQ 100
#define EMB 512
#define HID 1024
#define KDIM 1536

// ---------------- LSTM step: z = [x_t; h] @ W' (gates interleaved), fused gate epilogue ----------
// Tile 64x128, 4 waves (2m x 2n, wave 32x64), 256 threads, grid 512 -> 2 blocks/CU:
// two INDEPENDENT barriers per CU so one block's sync bubble is filled by the other block.
// BK=64, 3-deep LDS pipeline (72 KB), counted vmcnt (6/0), raw s_barrier, XCD-swizzled blocks.
__global__ __launch_bounds__(256, 2) void k_step(
    const u16* __restrict__ emb, const u16* __restrict__ W2T,
    const float* __restrict__ b2, const float* __restrict__ p_i,
    const float* __restrict__ p_f, const float* __restrict__ p_o,
    const int* __restrict__ tokQ, const int* __restrict__ tokR,
    const int* __restrict__ lenQ, const int* __restrict__ lenR,
    const u16* __restrict__ h_cur, u16* __restrict__ h_nxt,
    float* __restrict__ c_st, int t)
{
  __shared__ u16 sb[3 * 12288];  // 3 bufs x (lA 4096 u16 = 8 KB + lB 8192 u16 = 16 KB) = 72 KB
  const int tid = threadIdx.x;
  const int lane = tid & 63, wid = tid >> 6;       // 4 waves
  const int wm = wid >> 1, wn = wid & 1;           // 2m x 2n; wave tile 32 rows x 64 cols
  const int lane_lo = lane & 15, lane_hi = lane >> 4;
  // XCD-aware swizzle: XCD k (= g%8) owns bx in {4k..4k+3}, all 16 by.
  const int g = blockIdx.x;                         // 512 blocks
  const int bx = (g & 7) * 4 + ((g >> 3) & 3);      // 0..31
  const int by = g >> 5;                            // 0..15 (64-row tiles)

  f32x4 acc[2][4];
  const f32x4 zz = {0.f, 0.f, 0.f, 0.f};
#pragma unroll
  for (int a = 0; a < 2; ++a)
#pragma unroll
    for (int bb = 0; bb < 4; ++bb) acc[a][bb] = zz;

  // ---- token loads FIRST (longest dependency chain) ----
  int tokv[2], rowe[2], rowi[2], ldsoA[2], srcoA[2];
#pragma unroll
  for (int j = 0; j < 2; ++j) {
    const int ch = j * 256 + tid;        // A chunks 0..511; 8 chunks (128 B) per row
    const int r = ch >> 3;               // 0..63
    const int srcoff = ((ch & 7) ^ (r & 7)) * 8;   // zero-conflict XOR swizzle (u16 elems)
    const int m = by * 64 + r, e = m >> 9, i = m & 511;
    tokv[j] = (e ? tokR : tokQ)[i * LSEQ + t];
    rowe[j] = e; rowi[j] = i;
    srcoA[j] = srcoff;
    ldsoA[j] = ch * 8;                   // linear LDS dest (u16)
  }

  // ---- epilogue operand prefetch (oldest in vmcnt; hidden under K-loop) ----
  const int colbase = bx * 128 + wn * 64;
  const int h = ((colbase >> 6) << 4) + lane_lo;
  float b2v[4];
#pragma unroll
  for (int gg = 0; gg < 4; ++gg) b2v[gg] = b2[colbase + gg * 16 + lane_lo];
  const float pi = p_i[h], pf = p_f[h], po = p_o[h];
  int lenv[2][4];
  float cold[2][4];
  u16 hprev[2][4];
#pragma unroll
  for (int mi = 0; mi < 2; ++mi)
#pragma unroll
    for (int r = 0; r < 4; ++r) {
      const int m = by * 64 + wm * 32 + mi * 16 + lane_hi * 4 + r;
      const int e = m >> 9, i = m & 511;
      lenv[mi][r] = e ? lenR[i] : lenQ[i];
      const size_t ci = (size_t)(e * 512 + i) * HID + h;
      cold[mi][r] = c_st[ci];
      hprev[mi][r] = h_cur[ci];
    }
  __builtin_amdgcn_sched_barrier(0);  // pin: prologue vmem issued before stage 0

  // ---- staging pointers ----
  const u16* pAx[2];
  const u16* pAh[2];
  const u16* pB[4];
  int ldsoB[4];
#pragma unroll
  for (int j = 0; j < 2; ++j) {
    pAx[j] = emb + (size_t)tokv[j] * EMB + srcoA[j];
    pAh[j] = h_cur + (size_t)(rowe[j] * 512 + rowi[j]) * HID - 512 + srcoA[j];  // kb>=512 when used
  }
#pragma unroll
  for (int j = 0; j < 4; ++j) {
    const int ch = j * 256 + tid;        // B chunks 0..1023; 8 per row
    const int r = ch >> 3;               // 0..127
    const int srcoff = ((ch & 7) ^ (r & 7)) * 8;
    pB[j] = W2T + (size_t)(bx * 128 + r) * KDIM + srcoff;
    ldsoB[j] = ch * 8;
  }

  auto stage = [&](int kt, int buf) {
    const int kb = kt * 64;
    u16* lA = sb + buf * 12288;
    u16* lB = lA + 4096;
    const bool isx = kb < EMB;  // uniform per kt
#pragma unroll
    for (int j = 0; j < 2; ++j) ld_lds16((isx ? pAx[j] : pAh[j]) + kb, lA + ldsoA[j]);
#pragma unroll
    for (int j = 0; j < 4; ++j) ld_lds16(pB[j] + kb, lB + ldsoB[j]);
  };

  auto compute = [&](int buf) {
    const u16* lA = sb + buf * 12288;
    const u16* lB = lA + 4096;
#pragma unroll
    for (int kk = 0; kk < 2; ++kk) {
      bf16x8 aF[2], bF[4];
#pragma unroll
      for (int mi = 0; mi < 2; ++mi) {
        const int rr = wm * 32 + mi * 16 + lane_lo;
        const int byo = rr * 128 + ((kk * 64 + lane_hi * 16) ^ ((rr & 7) << 4));
        aF[mi] = *(const bf16x8*)((const char*)lA + byo);
      }
#pragma unroll
      for (int ni = 0; ni < 4; ++ni) {
        const int rr = wn * 64 + ni * 16 + lane_lo;
        const int byo = rr * 128 + ((kk * 64 + lane_hi * 16) ^ ((rr & 7) << 4));
        bF[ni] = *(const bf16x8*)((const char*)lB + byo);
      }
#pragma unroll
      for (int mi = 0; mi < 2; ++mi)
#pragma unroll
        for (int ni = 0; ni < 4; ++ni)
          acc[mi][ni] = __builtin_amdgcn_mfma_f32_16x16x32_bf16(aF[mi], bF[ni], acc[mi][ni], 0, 0, 0);
    }
  };

  // ---- prologue: 2 stages in flight (6 loads/thread each) ----
  stage(0, 0);
  stage(1, 1);

  // ---- K loop: 24 iters. wait stage kt (counted), barrier, prefetch kt+2, compute kt ----
  for (int kt = 0; kt < 24; ++kt) {
    if (kt < 23) asm volatile("s_waitcnt vmcnt(6)" ::: "memory");   // stage kt landed; kt+1 in flight
    else         asm volatile("s_waitcnt vmcnt(0)" ::: "memory");
    __builtin_amdgcn_s_barrier();
    __builtin_amdgcn_sched_barrier(0);
    if (kt < 22) stage(kt + 2, (kt + 2) % 3);
    __builtin_amdgcn_s_setprio(1);
    compute(kt % 3);
    __builtin_amdgcn_s_setprio(0);
  }

  // ----- fused gate epilogue: lane owns one h, 8 rows; ni == gate index -----
#pragma unroll
  for (int mi = 0; mi < 2; ++mi) {
#pragma unroll
    for (int r = 0; r < 4; ++r) {
      const int m = by * 64 + wm * 32 + mi * 16 + lane_hi * 4 + r;
      const int e = m >> 9, i = m & 511;
      const size_t ci = (size_t)(e * 512 + i) * HID + h;
      u16 hv;
      if (t < lenv[mi][r]) {
        const float c_old = cold[mi][r];
        const float zi = acc[mi][0][r] + b2v[0] + pi * c_old;
        const float zj = acc[mi][1][r] + b2v[1];
        const float zf = acc[mi][2][r] + b2v[2] + pf * c_old;  // FORGET_BIAS folded into b2
        const float zo = acc[mi][3][r] + b2v[3];
        const float ig = fsig(zi), fg = fsig(zf);
        const float cn = fg * c_old + ig * ftanhf(zj);
        const float og = fsig(zo + po * cn);
        const float hn = og * ftanhf(cn);
        c_st[ci] = cn;
        hv = f2bf(hn);
      } else {
        hv = hprev[mi][r];
      }
      h_nxt[ci] = hv;
    }
  }
}

// ---------------- generic bf16 GEMM: C[m][n] = sum_k A[m][k] * Bn[n][k] ----------------
template <int OUT_BF16>
__global__ __launch_bounds__(256) void k_gemm(
    const u16* __restrict__ A, const u16* __restrict__ Bn,
    void* __restrict__ Cout, int K, int ldc)
{
  __shared__ u16 lA[128 * 64];
  __shared__ u16 lB[128 * 64];
  const int tid = threadIdx.x;
  const int lane = tid & 63, wid = tid >> 6;
  const int wm = wid >> 1, wn = wid & 1;
  const int lane_lo = lane & 15, lane_hi = lane >> 4;
  const int bx = blockIdx.x, by = blockIdx.y;

  f32x4 acc[4][4];
  const f32x4 zz = {0.f, 0.f, 0.f, 0.f};
#pragma unroll
  for (int a = 0; a < 4; ++a)
#pragma unroll
    for (int bb = 0; bb < 4; ++bb) acc[a][bb] = zz;

  const int nkt = K >> 6;
  for (int kt = 0; kt < nkt; ++kt) {
    const int kb = kt * 64;
#pragma unroll
    for (int j = 0; j < 4; ++j) {
      const int cbase = (j * 4 + wid) * 64;
      const int ch = cbase + lane;
      const int r = ch >> 3;
      const int srcoff = ((((ch & 7) << 4) ^ ((r & 7) << 4)) >> 1);
      ld_lds16(A + (size_t)(by * 128 + r) * K + kb + srcoff, &lA[cbase * 8]);
    }
#pragma unroll
    for (int j = 0; j < 4; ++j) {
      const int cbase = (j * 4 + wid) * 64;
      const int ch = cbase + lane;
      const int r = ch >> 3;
      const int srcoff = ((((ch & 7) << 4) ^ ((r & 7) << 4)) >> 1);
      ld_lds16(Bn + (size_t)(bx * 128 + r) * K + kb + srcoff, &lB[cbase * 8]);
    }
    __syncthreads();
#pragma unroll
    for (int kk = 0; kk < 2; ++kk) {
      bf16x8 aF[4], bF[4];
#pragma unroll
      for (int mi = 0; mi < 4; ++mi) {
        const int rr = wm * 64 + mi * 16 + lane_lo;
        const int byo = rr * 128 + ((kk * 64 + lane_hi * 16) ^ ((rr & 7) << 4));
        aF[mi] = *(const bf16x8*)((const char*)lA + byo);
      }
#pragma unroll
      for (int ni = 0; ni < 4; ++ni) {
        const int rr = wn * 64 + ni * 16 + lane_lo;
        const int byo = rr * 128 + ((kk * 64 + lane_hi * 16) ^ ((rr & 7) << 4));
        bF[ni] = *(const bf16x8*)((const char*)lB + byo);
      }
#pragma unroll
      for (int mi = 0; mi < 4; ++mi)
#pragma unroll
        for (int ni = 0; ni < 4; ++ni)
          acc[mi][ni] = __builtin_amdgcn_mfma_f32_16x16x32_bf16(aF[mi], bF[ni], acc[mi][ni], 0, 0, 0);
    }
    __syncthreads();
  }

#pragma unroll
  for (int mi = 0; mi < 4; ++mi)
#pragma unroll
    for (int r = 0; r < 4; ++r) {
      const int m = by * 128 + wm * 64 + mi * 16 + lane_hi * 4 + r;
#pragma unroll
      for (int ni = 0; ni < 4; ++ni) {
        const int col = bx * 128 + wn * 64 + ni * 16 + lane_lo;
        const float v = acc[mi][ni][r];
        if (OUT_BF16) ((u16*)Cout)[(size_t)m * ldc + col] = f2bf(v);
        else ((float*)Cout)[(size_t)m * ldc + col] = v;
      }
    }
}

// ---------------- prep kernels ----------------
// out[n'][k] (bf16) = in[k][n] (f32); perm!=0 applies gate-interleave permutation (N_=4096)
__global__ void k_transpose(const float* __restrict__ in, u16* __restrict__ out,
                            int K_, int N_, int perm)
{
  __shared__ float tile[64][65];
  const int tid = threadIdx.x;
  const int k0 = blockIdx.y * 64, n0 = blockIdx.x * 64;
  const int c = tid & 63, rq = tid >> 6;
  for (int rr = 0; rr < 64; rr += 4)
    tile[rr + rq][c] = in[(size_t)(k0 + rr + rq) * N_ + n0 + c];
  __syncthreads();
  for (int nr0 = 0; nr0 < 64; nr0 += 4) {
    const int nr = nr0 + rq;
    const int n = n0 + nr;
    int np = n;
    if (perm) {
      const int g = n >> 10, hh = n & 1023;
      np = ((hh >> 4) << 6) + (g << 4) + (hh & 15);
    }
    out[(size_t)np * K_ + k0 + c] = f2bf(tile[c][nr]);
  }
}

__global__ void k_bias(const float* __restrict__ b, float* __restrict__ b2) {
  const int n = blockIdx.x * 256 + threadIdx.x;
  if (n < 4096) {
    const int g = n >> 10, hh = n & 1023;
    const int np = ((hh >> 4) << 6) + (g << 4) + (hh & 15);
    b2[np] = b[n] + (g == 2 ? 2.0f : 0.0f);
  }
}

__global__ void k_cvt(const float4* __restrict__ in, u16* __restrict__ out, size_t n4) {
  size_t idx = (size_t)blockIdx.x * blockDim.x + threadIdx.x;
  const size_t stride = (size_t)gridDim.x * blockDim.x;
  for (; idx < n4; idx += stride) {
    const float4 v = in[idx];
    ushort4 o;
    o.x = f2bf(v.x); o.y = f2bf(v.y); o.z = f2bf(v.z); o.w = f2bf(v.w);
    *(ushort4*)(out + idx * 4) = o;
  }
}

__global__ void k_zero(uint4* __restrict__ p, size_t n) {
  size_t idx = (size_t)blockIdx.x * blockDim.x + threadIdx.x;
  const size_t stride = (size_t)gridDim.x * blockDim.x;
  const uint4 z = {0u, 0u, 0u, 0u};
  for (; idx < n; idx += stride) p[idx] = z;
}

// ---------------- loss ----------------
__global__ void k_loss1(const float* __restrict__ D, float* __restrict__ part) {
  __shared__ float sd[256];
  const int tid = threadIdx.x;
  float s = 0.f;
  for (int idx = blockIdx.x * 256 + tid; idx < 512 * 512; idx += 256 * 256) {
    const float x = D[idx];
    float sp;
    if (x > 20.f) sp = x;
    else if (x < -20.f) sp = __expf(x);
    else sp = __logf(1.0f + __expf(x));
    if ((idx >> 9) == (idx & 511)) sp -= x;
    s += sp;
  }
  sd[tid] = s;
  __syncthreads();
  for (int o = 128; o > 0; o >>= 1) { if (tid < o) sd[tid] += sd[tid + o]; __syncthreads(); }
  if (tid == 0) part[blockIdx.x] = sd[0];
}

__global__ void k_loss2(const float* __restrict__ part, float* __restrict__ out) {
  __shared__ float sd[256];
  const int tid = threadIdx.x;
  sd[tid] = part[tid];
  __syncthreads();
  for (int o = 128; o > 0; o >>= 1) { if (tid < o) sd[tid] += sd[tid + o]; __syncthreads(); }
  if (tid == 0) out[0] = sd[0] * (1.0f / (512.0f * 512.0f));
}

// ---------------- launch ----------------
extern "C" void kernel_launch(void* const* d_in, const int* in_sizes, int n_in,
                              void* d_out, int out_size, void* d_ws, size_t ws_size,
                              hipStream_t stream)
{
  const float* embF = (const float*)d_in[0];
  const float* W    = (const float*)d_in[1];
  const float* b    = (const float*)d_in[2];
  const float* p_i  = (const float*)d_in[3];
  const float* p_f  = (const float*)d_in[4];
  const float* p_o  = (const float*)d_in[5];
  const float* Mm   = (const float*)d_in[6];
  const int* tokQ   = (const int*)d_in[7];
  const int* tokR   = (const int*)d_in[8];
  const int* lenQ   = (const int*)d_in[9];
  const int* lenR   = (const int*)d_in[10];
  float* out = (float*)d_out;

  char* ws = (char*)d_ws;
  const size_t OFF_EMB  = 0;                       // 50000*512*2 = 51,200,000
  const size_t OFF_W2T  = 51200000;                // 4096*1536*2 = 12,582,912
  const size_t OFF_MT   = OFF_W2T + 12582912;      // 1024*1024*2 =  2,097,152
  const size_t OFF_B2   = OFF_MT + 2097152;        // 4096*4
  const size_t OFF_H    = OFF_B2 + 16384;          // 2buf*2enc*512*1024*2 = 4,194,304
  const size_t OFF_C    = OFF_H + 4194304;         // 2enc*512*1024*4 = 4,194,304
  const size_t OFF_QT   = OFF_C + 4194304;         // 512*1024*2 = 1,048,576
  const size_t OFF_PART = OFF_QT + 1048576;        // 256*4
  const size_t NEED = OFF_PART + 1024;
  if (ws_size < NEED) return;  // workspace too small: bail (output stays invalid as a signal)

  u16* embB  = (u16*)(ws + OFF_EMB);
  u16* W2T   = (u16*)(ws + OFF_W2T);
  u16* MT    = (u16*)(ws + OFF_MT);
  float* b2  = (float*)(ws + OFF_B2);
  u16* hbuf  = (u16*)(ws + OFF_H);
  float* cst = (float*)(ws + OFF_C);
  u16* qt    = (u16*)(ws + OFF_QT);
  float* part= (float*)(ws + OFF_PART);

  // prep
  k_cvt<<<dim3(2048), dim3(256), 0, stream>>>((const float4*)embF, embB, (size_t)(50000 * 512 / 4));
  k_transpose<<<dim3(64, 24), dim3(256), 0, stream>>>(W, W2T, 1536, 4096, 1);
  k_transpose<<<dim3(16, 16), dim3(256), 0, stream>>>(Mm, MT, 1024, 1024, 0);
  k_bias<<<dim3(16), dim3(256), 0, stream>>>(b, b2);
  k_zero<<<dim3(256), dim3(256), 0, stream>>>((uint4*)hbuf, 131072);   // h buf0 (2 MB)
  k_zero<<<dim3(256), dim3(256), 0, stream>>>((uint4*)cst, 262144);    // c (4 MB)

  // recurrence: h double-buffered; t reads buf (t&1), writes buf ((t+1)&1); final state in buf 0
  const size_t HBUFSTRIDE = (size_t)2 * 512 * 1024;  // u16 elems per buffer
  for (int t = 0; t < 100; ++t) {
    u16* hc = hbuf + (size_t)(t & 1) * HBUFSTRIDE;
    u16* hn = hbuf + (size_t)((t + 1) & 1) * HBUFSTRIDE;
    k_step<<<dim3(512), dim3(256), 0, stream>>>(embB, W2T, b2, p_i, p_f, p_o,
                                                tokQ, tokR, lenQ, lenR, hc, hn, cst, t);
  }

  // q_t = h_q @ M  (A = enc0 of buf0; B = M^T rows)
  k_gemm<1><<<dim3(8, 4), dim3(256), 0, stream>>>(hbuf, MT, qt, 1024, 1024);
  // distances = q_t @ h_r^T  (B rows = enc1 final h)
  k_gemm<0><<<dim3(4, 4), dim3(256), 0, stream>>>(qt, hbuf + (size_t)512 * 1024, out, 1024, 512);

  k_loss1<<<dim3(256), dim3(256), 0, stream>>>(out, part);
  k_loss2<<<dim3(1), dim3(256), 0, stream>>>(part, out + 262144);
}

// Round 8
// 2091.412 us; speedup vs baseline: 1.1271x; 1.0065x over previous
//
#include <hip/hip_runtime.h>
#include <stdint.h>

typedef unsigned short u16;
typedef __bf16 bf16x8 __attribute__((ext_vector_type(8)));
typedef float f32x4 __attribute__((ext_vector_type(4)));

#define AS1 __attribute__((address_space(1)))
#define AS3 __attribute__((address_space(3)))

__device__ __forceinline__ void ld_lds16(const void* gp, void* lp) {
  __builtin_amdgcn_global_load_lds((AS1 void*)(void*)gp, (AS3 void*)lp, 16, 0, 0);
}

__device__ __forceinline__ u16 f2bf(float f) {
  uint32_t u = __float_as_uint(f);
  u += 0x7FFFu + ((u >> 16) & 1u);
  return (u16)(u >> 16);
}

__device__ __forceinline__ float fsig(float x) { return 1.0f / (1.0f + __expf(-x)); }
__device__ __forceinline__ float ftanhf(float x) {
  float e = __expf(-2.0f * fabsf(x));
  float t = (1.0f - e) / (1.0f + e);
  return copysignf(t, x);
}

#define LSEQ 100
#define EMB 512
#define HID 1024
#define KDIM 1536

// ---------------- LSTM step: z = [x_t; h] @ W' (gates interleaved), fused gate epilogue ----------
// Tile 64x128, 4 waves (2m x 2n, wave 32x64), 256 threads, grid 512 -> 2 blocks/CU:
// two INDEPENDENT barriers per CU so one block's sync bubble is filled by the other block.
// BK=64, 3-deep LDS pipeline (72 KB), counted vmcnt (6/0), raw s_barrier, XCD-swizzled blocks.
__global__ __launch_bounds__(256, 2) void k_step(
    const u16* __restrict__ emb, const u16* __restrict__ W2T,
    const float* __restrict__ b2, const float* __restrict__ p_i,
    const float* __restrict__ p_f, const float* __restrict__ p_o,
    const int* __restrict__ tokQ, const int* __restrict__ tokR,
    const int* __restrict__ lenQ, const int* __restrict__ lenR,
    const u16* __restrict__ h_cur, u16* __restrict__ h_nxt,
    float* __restrict__ c_st, int t)
{
  __shared__ u16 sb[3 * 12288];  // 3 bufs x (lA 4096 u16 = 8 KB + lB 8192 u16 = 16 KB) = 72 KB
  const int tid = threadIdx.x;
  const int lane = tid & 63, wid = tid >> 6;       // 4 waves
  const int wm = wid >> 1, wn = wid & 1;           // 2m x 2n; wave tile 32 rows x 64 cols
  const int lane_lo = lane & 15, lane_hi = lane >> 4;
  // XCD-aware swizzle: XCD k (= g%8) owns bx in {4k..4k+3}, all 16 by.
  const int g = blockIdx.x;                         // 512 blocks
  const int bx = (g & 7) * 4 + ((g >> 3) & 3);      // 0..31
  const int by = g >> 5;                            // 0..15 (64-row tiles)

  f32x4 acc[2][4];
  const f32x4 zz = {0.f, 0.f, 0.f, 0.f};
#pragma unroll
  for (int a = 0; a < 2; ++a)
#pragma unroll
    for (int bb = 0; bb < 4; ++bb) acc[a][bb] = zz;

  // ---- token loads FIRST (longest dependency chain) ----
  int tokv[2], rowe[2], rowi[2], ldsoA[2], srcoA[2];
#pragma unroll
  for (int j = 0; j < 2; ++j) {
    const int ch = j * 256 + tid;        // A chunks 0..511; 8 chunks (128 B) per row
    const int r = ch >> 3;               // 0..63
    const int srcoff = ((ch & 7) ^ (r & 7)) * 8;   // zero-conflict XOR swizzle (u16 elems)
    const int m = by * 64 + r, e = m >> 9, i = m & 511;
    tokv[j] = (e ? tokR : tokQ)[i * LSEQ + t];
    rowe[j] = e; rowi[j] = i;
    srcoA[j] = srcoff;
    ldsoA[j] = ch * 8;                   // linear LDS dest (u16)
  }

  // ---- epilogue operand prefetch (oldest in vmcnt; hidden under K-loop) ----
  const int colbase = bx * 128 + wn * 64;
  const int h = ((colbase >> 6) << 4) + lane_lo;
  float b2v[4];
#pragma unroll
  for (int gg = 0; gg < 4; ++gg) b2v[gg] = b2[colbase + gg * 16 + lane_lo];
  const float pi = p_i[h], pf = p_f[h], po = p_o[h];
  int lenv[2][4];
  float cold[2][4];
  u16 hprev[2][4];
#pragma unroll
  for (int mi = 0; mi < 2; ++mi)
#pragma unroll
    for (int r = 0; r < 4; ++r) {
      const int m = by * 64 + wm * 32 + mi * 16 + lane_hi * 4 + r;
      const int e = m >> 9, i = m & 511;
      lenv[mi][r] = e ? lenR[i] : lenQ[i];
      const size_t ci = (size_t)(e * 512 + i) * HID + h;
      cold[mi][r] = c_st[ci];
      hprev[mi][r] = h_cur[ci];
    }
  __builtin_amdgcn_sched_barrier(0);  // pin: prologue vmem issued before stage 0

  // ---- staging pointers ----
  const u16* pAx[2];
  const u16* pAh[2];
  const u16* pB[4];
  int ldsoB[4];
#pragma unroll
  for (int j = 0; j < 2; ++j) {
    pAx[j] = emb + (size_t)tokv[j] * EMB + srcoA[j];
    pAh[j] = h_cur + (size_t)(rowe[j] * 512 + rowi[j]) * HID - 512 + srcoA[j];  // kb>=512 when used
  }
#pragma unroll
  for (int j = 0; j < 4; ++j) {
    const int ch = j * 256 + tid;        // B chunks 0..1023; 8 per row
    const int r = ch >> 3;               // 0..127
    const int srcoff = ((ch & 7) ^ (r & 7)) * 8;
    pB[j] = W2T + (size_t)(bx * 128 + r) * KDIM + srcoff;
    ldsoB[j] = ch * 8;
  }

  auto stage = [&](int kt, int buf) {
    const int kb = kt * 64;
    u16* lA = sb + buf * 12288;
    u16* lB = lA + 4096;
    const bool isx = kb < EMB;  // uniform per kt
#pragma unroll
    for (int j = 0; j < 2; ++j) ld_lds16((isx ? pAx[j] : pAh[j]) + kb, lA + ldsoA[j]);
#pragma unroll
    for (int j = 0; j < 4; ++j) ld_lds16(pB[j] + kb, lB + ldsoB[j]);
  };

  auto compute = [&](int buf) {
    const u16* lA = sb + buf * 12288;
    const u16* lB = lA + 4096;
#pragma unroll
    for (int kk = 0; kk < 2; ++kk) {
      bf16x8 aF[2], bF[4];
#pragma unroll
      for (int mi = 0; mi < 2; ++mi) {
        const int rr = wm * 32 + mi * 16 + lane_lo;
        const int byo = rr * 128 + ((kk * 64 + lane_hi * 16) ^ ((rr & 7) << 4));
        aF[mi] = *(const bf16x8*)((const char*)lA + byo);
      }
#pragma unroll
      for (int ni = 0; ni < 4; ++ni) {
        const int rr = wn * 64 + ni * 16 + lane_lo;
        const int byo = rr * 128 + ((kk * 64 + lane_hi * 16) ^ ((rr & 7) << 4));
        bF[ni] = *(const bf16x8*)((const char*)lB + byo);
      }
#pragma unroll
      for (int mi = 0; mi < 2; ++mi)
#pragma unroll
        for (int ni = 0; ni < 4; ++ni)
          acc[mi][ni] = __builtin_amdgcn_mfma_f32_16x16x32_bf16(aF[mi], bF[ni], acc[mi][ni], 0, 0, 0);
    }
  };

  // ---- prologue: 2 stages in flight (6 loads/thread each) ----
  stage(0, 0);
  stage(1, 1);

  // ---- K loop: 24 iters. wait stage kt (counted), barrier, prefetch kt+2, compute kt ----
  for (int kt = 0; kt < 24; ++kt) {
    if (kt < 23) asm volatile("s_waitcnt vmcnt(6)" ::: "memory");   // stage kt landed; kt+1 in flight
    else         asm volatile("s_waitcnt vmcnt(0)" ::: "memory");
    __builtin_amdgcn_s_barrier();
    __builtin_amdgcn_sched_barrier(0);
    if (kt < 22) stage(kt + 2, (kt + 2) % 3);
    __builtin_amdgcn_s_setprio(1);
    compute(kt % 3);
    __builtin_amdgcn_s_setprio(0);
  }

  // ----- fused gate epilogue: lane owns one h, 8 rows; ni == gate index -----
#pragma unroll
  for (int mi = 0; mi < 2; ++mi) {
#pragma unroll
    for (int r = 0; r < 4; ++r) {
      const int m = by * 64 + wm * 32 + mi * 16 + lane_hi * 4 + r;
      const int e = m >> 9, i = m & 511;
      const size_t ci = (size_t)(e * 512 + i) * HID + h;
      u16 hv;
      if (t < lenv[mi][r]) {
        const float c_old = cold[mi][r];
        const float zi = acc[mi][0][r] + b2v[0] + pi * c_old;
        const float zj = acc[mi][1][r] + b2v[1];
        const float zf = acc[mi][2][r] + b2v[2] + pf * c_old;  // FORGET_BIAS folded into b2
        const float zo = acc[mi][3][r] + b2v[3];
        const float ig = fsig(zi), fg = fsig(zf);
        const float cn = fg * c_old + ig * ftanhf(zj);
        const float og = fsig(zo + po * cn);
        const float hn = og * ftanhf(cn);
        c_st[ci] = cn;
        hv = f2bf(hn);
      } else {
        hv = hprev[mi][r];
      }
      h_nxt[ci] = hv;
    }
  }
}

// ---------------- generic bf16 GEMM: C[m][n] = sum_k A[m][k] * Bn[n][k] ----------------
template <int OUT_BF16>
__global__ __launch_bounds__(256) void k_gemm(
    const u16* __restrict__ A, const u16* __restrict__ Bn,
    void* __restrict__ Cout, int K, int ldc)
{
  __shared__ u16 lA[128 * 64];
  __shared__ u16 lB[128 * 64];
  const int tid = threadIdx.x;
  const int lane = tid & 63, wid = tid >> 6;
  const int wm = wid >> 1, wn = wid & 1;
  const int lane_lo = lane & 15, lane_hi = lane >> 4;
  const int bx = blockIdx.x, by = blockIdx.y;

  f32x4 acc[4][4];
  const f32x4 zz = {0.f, 0.f, 0.f, 0.f};
#pragma unroll
  for (int a = 0; a < 4; ++a)
#pragma unroll
    for (int bb = 0; bb < 4; ++bb) acc[a][bb] = zz;

  const int nkt = K >> 6;
  for (int kt = 0; kt < nkt; ++kt) {
    const int kb = kt * 64;
#pragma unroll
    for (int j = 0; j < 4; ++j) {
      const int cbase = (j * 4 + wid) * 64;
      const int ch = cbase + lane;
      const int r = ch >> 3;
      const int srcoff = ((((ch & 7) << 4) ^ ((r & 7) << 4)) >> 1);
      ld_lds16(A + (size_t)(by * 128 + r) * K + kb + srcoff, &lA[cbase * 8]);
    }
#pragma unroll
    for (int j = 0; j < 4; ++j) {
      const int cbase = (j * 4 + wid) * 64;
      const int ch = cbase + lane;
      const int r = ch >> 3;
      const int srcoff = ((((ch & 7) << 4) ^ ((r & 7) << 4)) >> 1);
      ld_lds16(Bn + (size_t)(bx * 128 + r) * K + kb + srcoff, &lB[cbase * 8]);
    }
    __syncthreads();
#pragma unroll
    for (int kk = 0; kk < 2; ++kk) {
      bf16x8 aF[4], bF[4];
#pragma unroll
      for (int mi = 0; mi < 4; ++mi) {
        const int rr = wm * 64 + mi * 16 + lane_lo;
        const int byo = rr * 128 + ((kk * 64 + lane_hi * 16) ^ ((rr & 7) << 4));
        aF[mi] = *(const bf16x8*)((const char*)lA + byo);
      }
#pragma unroll
      for (int ni = 0; ni < 4; ++ni) {
        const int rr = wn * 64 + ni * 16 + lane_lo;
        const int byo = rr * 128 + ((kk * 64 + lane_hi * 16) ^ ((rr & 7) << 4));
        bF[ni] = *(const bf16x8*)((const char*)lB + byo);
      }
#pragma unroll
      for (int mi = 0; mi < 4; ++mi)
#pragma unroll
        for (int ni = 0; ni < 4; ++ni)
          acc[mi][ni] = __builtin_amdgcn_mfma_f32_16x16x32_bf16(aF[mi], bF[ni], acc[mi][ni], 0, 0, 0);
    }
    __syncthreads();
  }

#pragma unroll
  for (int mi = 0; mi < 4; ++mi)
#pragma unroll
    for (int r = 0; r < 4; ++r) {
      const int m = by * 128 + wm * 64 + mi * 16 + lane_hi * 4 + r;
#pragma unroll
      for (int ni = 0; ni < 4; ++ni) {
        const int col = bx * 128 + wn * 64 + ni * 16 + lane_lo;
        const float v = acc[mi][ni][r];
        if (OUT_BF16) ((u16*)Cout)[(size_t)m * ldc + col] = f2bf(v);
        else ((float*)Cout)[(size_t)m * ldc + col] = v;
      }
    }
}

// ---------------- prep kernels ----------------
// out[n'][k] (bf16) = in[k][n] (f32); perm!=0 applies gate-interleave permutation (N_=4096)
__global__ void k_transpose(const float* __restrict__ in, u16* __restrict__ out,
                            int K_, int N_, int perm)
{
  __shared__ float tile[64][65];
  const int tid = threadIdx.x;
  const int k0 = blockIdx.y * 64, n0 = blockIdx.x * 64;
  const int c = tid & 63, rq = tid >> 6;
  for (int rr = 0; rr < 64; rr += 4)
    tile[rr + rq][c] = in[(size_t)(k0 + rr + rq) * N_ + n0 + c];
  __syncthreads();
  for (int nr0 = 0; nr0 < 64; nr0 += 4) {
    const int nr = nr0 + rq;
    const int n = n0 + nr;
    int np = n;
    if (perm) {
      const int g = n >> 10, hh = n & 1023;
      np = ((hh >> 4) << 6) + (g << 4) + (hh & 15);
    }
    out[(size_t)np * K_ + k0 + c] = f2bf(tile[c][nr]);
  }
}

__global__ void k_bias(const float* __restrict__ b, float* __restrict__ b2) {
  const int n = blockIdx.x * 256 + threadIdx.x;
  if (n < 4096) {
    const int g = n >> 10, hh = n & 1023;
    const int np = ((hh >> 4) << 6) + (g << 4) + (hh & 15);
    b2[np] = b[n] + (g == 2 ? 2.0f : 0.0f);
  }
}

__global__ void k_cvt(const float4* __restrict__ in, u16* __restrict__ out, size_t n4) {
  size_t idx = (size_t)blockIdx.x * blockDim.x + threadIdx.x;
  const size_t stride = (size_t)gridDim.x * blockDim.x;
  for (; idx < n4; idx += stride) {
    const float4 v = in[idx];
    ushort4 o;
    o.x = f2bf(v.x); o.y = f2bf(v.y); o.z = f2bf(v.z); o.w = f2bf(v.w);
    *(ushort4*)(out + idx * 4) = o;
  }
}

__global__ void k_zero(uint4* __restrict__ p, size_t n) {
  size_t idx = (size_t)blockIdx.x * blockDim.x + threadIdx.x;
  const size_t stride = (size_t)gridDim.x * blockDim.x;
  const uint4 z = {0u, 0u, 0u, 0u};
  for (; idx < n; idx += stride) p[idx] = z;
}

// ---------------- loss ----------------
__global__ void k_loss1(const float* __restrict__ D, float* __restrict__ part) {
  __shared__ float sd[256];
  const int tid = threadIdx.x;
  float s = 0.f;
  for (int idx = blockIdx.x * 256 + tid; idx < 512 * 512; idx += 256 * 256) {
    const float x = D[idx];
    float sp;
    if (x > 20.f) sp = x;
    else if (x < -20.f) sp = __expf(x);
    else sp = __logf(1.0f + __expf(x));
    if ((idx >> 9) == (idx & 511)) sp -= x;
    s += sp;
  }
  sd[tid] = s;
  __syncthreads();
  for (int o = 128; o > 0; o >>= 1) { if (tid < o) sd[tid] += sd[tid + o]; __syncthreads(); }
  if (tid == 0) part[blockIdx.x] = sd[0];
}

__global__ void k_loss2(const float* __restrict__ part, float* __restrict__ out) {
  __shared__ float sd[256];
  const int tid = threadIdx.x;
  sd[tid] = part[tid];
  __syncthreads();
  for (int o = 128; o > 0; o >>= 1) { if (tid < o) sd[tid] += sd[tid + o]; __syncthreads(); }
  if (tid == 0) out[0] = sd[0] * (1.0f / (512.0f * 512.0f));
}

// ---------------- launch ----------------
extern "C" void kernel_launch(void* const* d_in, const int* in_sizes, int n_in,
                              void* d_out, int out_size, void* d_ws, size_t ws_size,
                              hipStream_t stream)
{
  const float* embF = (const float*)d_in[0];
  const float* W    = (const float*)d_in[1];
  const float* b    = (const float*)d_in[2];
  const float* p_i  = (const float*)d_in[3];
  const float* p_f  = (const float*)d_in[4];
  const float* p_o  = (const float*)d_in[5];
  const float* Mm   = (const float*)d_in[6];
  const int* tokQ   = (const int*)d_in[7];
  const int* tokR   = (const int*)d_in[8];
  const int* lenQ   = (const int*)d_in[9];
  const int* lenR   = (const int*)d_in[10];
  float* out = (float*)d_out;

  char* ws = (char*)d_ws;
  const size_t OFF_EMB  = 0;                       // 50000*512*2 = 51,200,000
  const size_t OFF_W2T  = 51200000;                // 4096*1536*2 = 12,582,912
  const size_t OFF_MT   = OFF_W2T + 12582912;      // 1024*1024*2 =  2,097,152
  const size_t OFF_B2   = OFF_MT + 2097152;        // 4096*4
  const size_t OFF_H    = OFF_B2 + 16384;          // 2buf*2enc*512*1024*2 = 4,194,304
  const size_t OFF_C    = OFF_H + 4194304;         // 2enc*512*1024*4 = 4,194,304
  const size_t OFF_QT   = OFF_C + 4194304;         // 512*1024*2 = 1,048,576
  const size_t OFF_PART = OFF_QT + 1048576;        // 256*4
  const size_t NEED = OFF_PART + 1024;
  if (ws_size < NEED) return;  // workspace too small: bail (output stays invalid as a signal)

  u16* embB  = (u16*)(ws + OFF_EMB);
  u16* W2T   = (u16*)(ws + OFF_W2T);
  u16* MT    = (u16*)(ws + OFF_MT);
  float* b2  = (float*)(ws + OFF_B2);
  u16* hbuf  = (u16*)(ws + OFF_H);
  float* cst = (float*)(ws + OFF_C);
  u16* qt    = (u16*)(ws + OFF_QT);
  float* part= (float*)(ws + OFF_PART);

  // prep
  k_cvt<<<dim3(2048), dim3(256), 0, stream>>>((const float4*)embF, embB, (size_t)(50000 * 512 / 4));
  k_transpose<<<dim3(64, 24), dim3(256), 0, stream>>>(W, W2T, 1536, 4096, 1);
  k_transpose<<<dim3(16, 16), dim3(256), 0, stream>>>(Mm, MT, 1024, 1024, 0);
  k_bias<<<dim3(16), dim3(256), 0, stream>>>(b, b2);
  k_zero<<<dim3(256), dim3(256), 0, stream>>>((uint4*)hbuf, 131072);   // h buf0 (2 MB)
  k_zero<<<dim3(256), dim3(256), 0, stream>>>((uint4*)cst, 262144);    // c (4 MB)

  // recurrence: h double-buffered; t reads buf (t&1), writes buf ((t+1)&1); final state in buf 0
  const size_t HBUFSTRIDE = (size_t)2 * 512 * 1024;  // u16 elems per buffer
  for (int t = 0; t < 100; ++t) {
    u16* hc = hbuf + (size_t)(t & 1) * HBUFSTRIDE;
    u16* hn = hbuf + (size_t)((t + 1) & 1) * HBUFSTRIDE;
    k_step<<<dim3(512), dim3(256), 0, stream>>>(embB, W2T, b2, p_i, p_f, p_o,
                                                tokQ, tokR, lenQ, lenR, hc, hn, cst, t);
  }

  // q_t = h_q @ M  (A = enc0 of buf0; B = M^T rows)
  k_gemm<1><<<dim3(8, 4), dim3(256), 0, stream>>>(hbuf, MT, qt, 1024, 1024);
  // distances = q_t @ h_r^T  (B rows = enc1 final h)
  k_gemm<0><<<dim3(4, 4), dim3(256), 0, stream>>>(qt, hbuf + (size_t)512 * 1024, out, 1024, 512);

  k_loss1<<<dim3(256), dim3(256), 0, stream>>>(out, part);
  k_loss2<<<dim3(1), dim3(256), 0, stream>>>(part, out + 262144);
}